// Round 1
// baseline (1300.387 us; speedup 1.0000x reference)
//
#include <hip/hip_runtime.h>
#include <math.h>
#include <float.h>

#define NB    65536
#define DIN   1408
#define PDIM  256
#define KCB   64
#define TAU   5e-4f   // widened: bf16x3 GEMM adds ~3e-5 dist error (fp64 refine covers flags)

// ---------------- workspace layout ----------------
// [0]       int    cnt (ambiguous-row counter; zeroed via memsetAsync)
// [64]      int    cand[NB]
// [262208]  int    list[NB]
// [524352]  double partials[NB/4]        (16384 * 8 = 131072 B)
// [1048832] float  g[NB*PDIM]
#define OFF_CNT   0
#define OFF_CAND  64
#define OFF_LIST  262208
#define OFF_PART  524352
#define OFF_G     1048832

typedef short bf16x8 __attribute__((ext_vector_type(8)));
typedef float f32x4  __attribute__((ext_vector_type(4)));

static __device__ __forceinline__ float wave_sum(float v) {
#pragma unroll
  for (int m = 32; m; m >>= 1) v += __shfl_xor(v, m, 64);
  return v;
}

// split fp32 -> bf16 hi (truncation; exact residual) ; lo = x - hi
static __device__ __forceinline__ ushort4 split_hi(float4 v, float4& lo) {
  unsigned int ux = __float_as_uint(v.x), uy = __float_as_uint(v.y),
               uz = __float_as_uint(v.z), uw = __float_as_uint(v.w);
  lo.x = v.x - __uint_as_float(ux & 0xffff0000u);
  lo.y = v.y - __uint_as_float(uy & 0xffff0000u);
  lo.z = v.z - __uint_as_float(uz & 0xffff0000u);
  lo.w = v.w - __uint_as_float(uw & 0xffff0000u);
  return make_ushort4((unsigned short)(ux >> 16), (unsigned short)(uy >> 16),
                      (unsigned short)(uz >> 16), (unsigned short)(uw >> 16));
}
static __device__ __forceinline__ ushort4 rne4(float4 v) {
  return make_ushort4((unsigned short)((__float_as_uint(v.x) + 0x8000u) >> 16),
                      (unsigned short)((__float_as_uint(v.y) + 0x8000u) >> 16),
                      (unsigned short)((__float_as_uint(v.z) + 0x8000u) >> 16),
                      (unsigned short)((__float_as_uint(v.w) + 0x8000u) >> 16));
}

// K2: g = (A @ W) * inv_row_norm via bf16x3 MFMA split GEMM.
// block = 128 rows x 256 cols, 512 threads = 8 waves (2 M x 4 N), 64x64 per wave.
// KT=32 fp32 k per tile, 44 tiles. A tile reg->cvt->LDS [row][k]; W tile
// reg->cvt->LDS transposed [n][k] so both fragment loads are ds_read_b128.
#define ROWS 40   // padded LDS row length (ushorts): 80 B rows, 2-way banks (free)
__global__ __launch_bounds__(512, 2) void k2_gemm(const float* __restrict__ A,
                                                  const float* __restrict__ W,
                                                  float* __restrict__ g) {
  __shared__ unsigned short As_hi[128][ROWS], As_lo[128][ROWS];
  __shared__ unsigned short Ws_hi[PDIM][ROWS], Ws_lo[PDIM][ROWS];
  __shared__ float rn[128];
  const int t = threadIdx.x;
  const int lane = t & 63;
  const int wm = (t >> 6) >> 2, wn = (t >> 6) & 3;   // wave grid 2 x 4
  const int row0 = blockIdx.x * 128;
  // A staging: thread covers row ar, k = ak..ak+7 (two float4)
  const int ar = t >> 2, ak = (t & 3) << 3;
  // W staging: thread covers col wcol, k = wkg..wkg+15 (16 strided scalars)
  const int wcol = t >> 1, wkg = (t & 1) << 4;
  const float* Ap = A + (size_t)(row0 + ar) * DIN + ak;
  const float* Wp = W + (size_t)wkg * PDIM + wcol;

  const f32x4 zero = {0.f, 0.f, 0.f, 0.f};
  f32x4 acc[4][4];
#pragma unroll
  for (int i = 0; i < 4; ++i)
#pragma unroll
    for (int j = 0; j < 4; ++j) acc[i][j] = zero;

  // prologue: load tile 0 into regs
  float4 a0 = *(const float4*)(Ap);
  float4 a1 = *(const float4*)(Ap + 4);
  float wv[16];
#pragma unroll
  for (int i = 0; i < 16; ++i) wv[i] = Wp[(size_t)i * PDIM];

  float ss = 0.f;
  for (int k0 = 0; k0 < DIN; k0 += 32) {
    // row sum-of-squares from the exact fp32 staging values
    ss += a0.x * a0.x + a0.y * a0.y + a0.z * a0.z + a0.w * a0.w
        + a1.x * a1.x + a1.y * a1.y + a1.z * a1.z + a1.w * a1.w;
    // convert current tile -> LDS
    {
      float4 lo;
      ushort4 h = split_hi(a0, lo);
      *(ushort4*)&As_hi[ar][ak] = h;
      *(ushort4*)&As_lo[ar][ak] = rne4(lo);
      h = split_hi(a1, lo);
      *(ushort4*)&As_hi[ar][ak + 4] = h;
      *(ushort4*)&As_lo[ar][ak + 4] = rne4(lo);
#pragma unroll
      for (int q = 0; q < 4; ++q) {
        float4 wva = make_float4(wv[4 * q], wv[4 * q + 1], wv[4 * q + 2], wv[4 * q + 3]);
        float4 wlo;
        ushort4 wh = split_hi(wva, wlo);
        *(ushort4*)&Ws_hi[wcol][wkg + 4 * q] = wh;
        *(ushort4*)&Ws_lo[wcol][wkg + 4 * q] = rne4(wlo);
      }
    }
    __syncthreads();
    // prefetch next tile into regs (overlaps the MFMA block below)
    const int kn = (k0 + 32 < DIN) ? k0 + 32 : 0;   // last iter: benign reload of tile 0
    float4 na0 = *(const float4*)(Ap + kn);
    float4 na1 = *(const float4*)(Ap + kn + 4);
    float nwv[16];
#pragma unroll
    for (int i = 0; i < 16; ++i) nwv[i] = Wp[(size_t)(kn + i) * PDIM];

    // fragment loads + 3-product MFMA
    {
      const int fr = lane & 15, fq = (lane >> 4) << 3;
      bf16x8 ah[4], al[4], bh[4], bl[4];
#pragma unroll
      for (int mf = 0; mf < 4; ++mf) {
        const int r = (wm << 6) + (mf << 4) + fr;
        ah[mf] = *(const bf16x8*)&As_hi[r][fq];
        al[mf] = *(const bf16x8*)&As_lo[r][fq];
      }
#pragma unroll
      for (int nf = 0; nf < 4; ++nf) {
        const int n = (wn << 6) + (nf << 4) + fr;
        bh[nf] = *(const bf16x8*)&Ws_hi[n][fq];
        bl[nf] = *(const bf16x8*)&Ws_lo[n][fq];
      }
#pragma unroll
      for (int mf = 0; mf < 4; ++mf)
#pragma unroll
        for (int nf = 0; nf < 4; ++nf) {
          acc[mf][nf] = __builtin_amdgcn_mfma_f32_16x16x32_bf16(ah[mf], bh[nf], acc[mf][nf], 0, 0, 0);
          acc[mf][nf] = __builtin_amdgcn_mfma_f32_16x16x32_bf16(al[mf], bh[nf], acc[mf][nf], 0, 0, 0);
          acc[mf][nf] = __builtin_amdgcn_mfma_f32_16x16x32_bf16(ah[mf], bl[nf], acc[mf][nf], 0, 0, 0);
        }
    }
    __syncthreads();
    a0 = na0; a1 = na1;
#pragma unroll
    for (int i = 0; i < 16; ++i) wv[i] = nwv[i];
  }

  // reduce the 4 staging partials per row (threads 4r..4r+3 are wave-adjacent)
  ss += __shfl_xor(ss, 1, 64);
  ss += __shfl_xor(ss, 2, 64);
  if ((t & 3) == 0) rn[ar] = ss;
  __syncthreads();
  if (t < 128) rn[t] = 1.0f / fmaxf(sqrtf(rn[t]), 1e-12f);
  __syncthreads();

  // C/D layout: col = lane&15, row = (lane>>4)*4 + reg  [m89-verified]
  const int er = lane & 15, eq = (lane >> 4) << 2;
#pragma unroll
  for (int mf = 0; mf < 4; ++mf) {
#pragma unroll
    for (int nf = 0; nf < 4; ++nf) {
#pragma unroll
      for (int r = 0; r < 4; ++r) {
        const int row = (wm << 6) + (mf << 4) + eq + r;
        const int col = (wn << 6) + (nf << 4) + er;
        g[(size_t)(row0 + row) * PDIM + col] = acc[mf][nf][r] * rn[row];
      }
    }
  }
}

// K3: per-row epilogue: h = g + b -> LayerNorm -> l2norm -> z,
// fp32 dists to codebook, top-2 argmin, flag ambiguous rows,
// write out row = codebook[i1], index, per-block fp64 loss partial.
__global__ __launch_bounds__(256) void k3_epilogue(const float* __restrict__ g,
                                                   const float* __restrict__ bvec,
                                                   const float* __restrict__ gamma,
                                                   const float* __restrict__ beta,
                                                   const float* __restrict__ C,
                                                   float* __restrict__ out,
                                                   int* __restrict__ cand,
                                                   int* __restrict__ list,
                                                   int* __restrict__ cnt,
                                                   double* __restrict__ partials) {
  __shared__ float zsh[4][260];
  __shared__ float lp[4];
  const int wave = threadIdx.x >> 6, lane = threadIdx.x & 63;
  const int row = blockIdx.x * 4 + wave;

  float4 gv = *(const float4*)(g + (size_t)row * PDIM + (lane << 2));
  float4 bv = *(const float4*)(bvec + (lane << 2));
  float h0 = gv.x + bv.x, h1 = gv.y + bv.y;
  float h2 = gv.z + bv.z, h3 = gv.w + bv.w;

  float mu = wave_sum(h0 + h1 + h2 + h3) * (1.0f / 256.0f);
  float d0 = h0 - mu, d1 = h1 - mu, d2 = h2 - mu, d3 = h3 - mu;
  float var = wave_sum(d0 * d0 + d1 * d1 + d2 * d2 + d3 * d3) * (1.0f / 256.0f);
  float invs = 1.0f / sqrtf(var + 1e-5f);
  float4 gm = *(const float4*)(gamma + (lane << 2));
  float4 bt = *(const float4*)(beta + (lane << 2));
  float zp0 = d0 * invs * gm.x + bt.x, zp1 = d1 * invs * gm.y + bt.y;
  float zp2 = d2 * invs * gm.z + bt.z, zp3 = d3 * invs * gm.w + bt.w;
  float nz = wave_sum(zp0 * zp0 + zp1 * zp1 + zp2 * zp2 + zp3 * zp3);
  float zn = 1.0f / fmaxf(sqrtf(nz), 1e-12f);
  float z0 = zp0 * zn, z1 = zp1 * zn, z2 = zp2 * zn, z3 = zp3 * zn;

  float4 zf = {z0, z1, z2, z3};
  float zz = wave_sum(z0 * z0 + z1 * z1 + z2 * z2 + z3 * z3);

  *(float4*)&zsh[wave][lane << 2] = zf;
  __syncthreads();

  // lane == codebook index k
  const float4* crow = (const float4*)(C + (size_t)lane * PDIM);
  float p = 0.f, cc = 0.f;
#pragma unroll 8
  for (int c4 = 0; c4 < 64; ++c4) {
    float4 cv = crow[c4];
    float4 zv = *(const float4*)&zsh[wave][c4 << 2];
    p += zv.x * cv.x + zv.y * cv.y + zv.z * cv.z + zv.w * cv.w;
    cc += cv.x * cv.x + cv.y * cv.y + cv.z * cv.z + cv.w * cv.w;
  }
  float dist = zz - 2.0f * p + cc;

  // top-2 butterfly reduce, first-index tiebreak on the min
  float b1 = dist; int i1 = lane; float b2 = FLT_MAX;
#pragma unroll
  for (int m = 32; m; m >>= 1) {
    float ob1 = __shfl_xor(b1, m, 64);
    int oi1 = __shfl_xor(i1, m, 64);
    float ob2 = __shfl_xor(b2, m, 64);
    if (ob1 < b1 || (ob1 == b1 && oi1 < i1)) {
      b2 = fminf(b1, ob2);
      b1 = ob1; i1 = oi1;
    } else {
      b2 = fminf(b2, ob1);
    }
  }
  if (lane == 0) {
    cand[row] = i1;
    if (b2 - b1 < TAU) {
      int w = atomicAdd(cnt, 1);
      list[w] = row;
    }
  }
  i1 = __shfl(i1, 0, 64);

  // straight-through forward value: out row = codebook[i1]; loss partial
  float4 cv = *(const float4*)(C + (size_t)i1 * PDIM + (lane << 2));
  *(float4*)(out + (size_t)row * PDIM + (lane << 2)) = cv;
  float e0 = cv.x - z0, e1 = cv.y - z1, e2 = cv.z - z2, e3 = cv.w - z3;
  float l = wave_sum(e0 * e0 + e1 * e1 + e2 * e2 + e3 * e3);
  if (lane == 0) {
    out[(size_t)NB * PDIM + row] = (float)i1;
    lp[wave] = l;
  }
  __syncthreads();
  if (threadIdx.x == 0)
    partials[blockIdx.x] =
        (double)lp[0] + (double)lp[1] + (double)lp[2] + (double)lp[3];
}

// K4: fp64 recompute of flagged rows; fix index, output row, loss partial.
__global__ __launch_bounds__(256) void k4_refine(const float* __restrict__ A,
                                                 const float* __restrict__ W,
                                                 const float* __restrict__ bvec,
                                                 const float* __restrict__ gamma,
                                                 const float* __restrict__ beta,
                                                 const float* __restrict__ C,
                                                 const int* __restrict__ list,
                                                 const int* __restrict__ cnt,
                                                 int* __restrict__ cand,
                                                 float* __restrict__ out,
                                                 double* __restrict__ partials) {
  __shared__ double xs[DIN];
  __shared__ double red[256];
  __shared__ double zd[PDIM];
  __shared__ int idx2[2];   // [0]=new, [1]=old
  const int t = threadIdx.x;
  const int n = *cnt;
  for (int it = blockIdx.x; it < n; it += gridDim.x) {
    const int row = list[it];
    __syncthreads();
    for (int i = t; i < DIN; i += 256) xs[i] = (double)A[(size_t)row * DIN + i];
    __syncthreads();
    double s = 0.0;
    for (int i = t; i < DIN; i += 256) s += xs[i] * xs[i];
    red[t] = s; __syncthreads();
    for (int m = 128; m; m >>= 1) { if (t < m) red[t] += red[t + m]; __syncthreads(); }
    const double inv = 1.0 / fmax(sqrt(red[0]), 1e-12);

    double gj = 0.0;
#pragma unroll 8
    for (int k = 0; k < DIN; ++k) gj += xs[k] * (double)W[(size_t)k * PDIM + t];
    const double h = gj * inv + (double)bvec[t];

    __syncthreads(); red[t] = h; __syncthreads();
    for (int m = 128; m; m >>= 1) { if (t < m) red[t] += red[t + m]; __syncthreads(); }
    const double mu = red[0] * (1.0 / 256.0);
    const double d = h - mu;
    __syncthreads(); red[t] = d * d; __syncthreads();
    for (int m = 128; m; m >>= 1) { if (t < m) red[t] += red[t + m]; __syncthreads(); }
    const double invs = 1.0 / sqrt(red[0] * (1.0 / 256.0) + 1e-5);
    const double zp = d * invs * (double)gamma[t] + (double)beta[t];
    __syncthreads(); red[t] = zp * zp; __syncthreads();
    for (int m = 128; m; m >>= 1) { if (t < m) red[t] += red[t + m]; __syncthreads(); }
    const double zn = 1.0 / fmax(sqrt(red[0]), 1e-12);
    const double z = zp * zn;
    zd[t] = z;
    __syncthreads(); red[t] = z * z; __syncthreads();
    for (int m = 128; m; m >>= 1) { if (t < m) red[t] += red[t + m]; __syncthreads(); }
    const double zz = red[0];
    __syncthreads();
    if (t < KCB) {
      double p = 0.0, cc = 0.0;
      for (int c = 0; c < PDIM; ++c) {
        double cv = (double)C[(size_t)t * PDIM + c];
        p += zd[c] * cv; cc += cv * cv;
      }
      red[t] = zz - 2.0 * p + cc;   // == sum((c_t - z)^2) in exact arithmetic
    }
    __syncthreads();
    if (t == 0) {
      double best = red[0]; int bi = 0;
      for (int k = 1; k < KCB; ++k) if (red[k] < best) { best = red[k]; bi = k; }
      const int old = cand[row];
      idx2[0] = bi; idx2[1] = old;
      if (bi != old) {
        cand[row] = bi;
        out[(size_t)NB * PDIM + row] = (float)bi;
        atomicAdd(&partials[row >> 2], red[bi] - red[old]);
      }
    }
    __syncthreads();
    if (idx2[0] != idx2[1])
      out[(size_t)row * PDIM + t] = C[(size_t)idx2[0] * PDIM + t];
    __syncthreads();
  }
}

// K6: reduce loss partials, write scalar.
__global__ __launch_bounds__(256) void k6_finalize(const double* __restrict__ partials,
                                                   float* __restrict__ out) {
  __shared__ double red[256];
  const int t = threadIdx.x;
  double s = 0.0;
  for (int i = t; i < NB / 4; i += 256) s += partials[i];
  red[t] = s; __syncthreads();
  for (int m = 128; m; m >>= 1) { if (t < m) red[t] += red[t + m]; __syncthreads(); }
  if (t == 0)
    out[(size_t)NB * PDIM + NB] = (float)(0.25 * red[0] / ((double)NB * (double)PDIM));
}

extern "C" void kernel_launch(void* const* d_in, const int* in_sizes, int n_in,
                              void* d_out, int out_size, void* d_ws, size_t ws_size,
                              hipStream_t stream) {
  const float* z_frame  = (const float*)d_in[0];
  const float* W        = (const float*)d_in[1];
  const float* bvec     = (const float*)d_in[2];
  const float* gamma    = (const float*)d_in[3];
  const float* beta     = (const float*)d_in[4];
  const float* codebook = (const float*)d_in[5];
  float* out = (float*)d_out;

  char* ws = (char*)d_ws;
  int*    cnt      = (int*)(ws + OFF_CNT);
  int*    cand     = (int*)(ws + OFF_CAND);
  int*    list     = (int*)(ws + OFF_LIST);
  double* partials = (double*)(ws + OFF_PART);
  float*  g        = (float*)(ws + OFF_G);

  hipMemsetAsync(ws + OFF_CNT, 0, 64, stream);

  k2_gemm<<<NB / 128, 512, 0, stream>>>(z_frame, W, g);
  k3_epilogue<<<NB / 4, 256, 0, stream>>>(g, bvec, gamma, beta, codebook,
                                          out, cand, list, cnt, partials);
  k4_refine<<<256, 256, 0, stream>>>(z_frame, W, bvec, gamma, beta, codebook,
                                     list, cnt, cand, out, partials);
  k6_finalize<<<1, 256, 0, stream>>>(partials, out);
}

// Round 2
// 917.342 us; speedup vs baseline: 1.4176x; 1.4176x over previous
//
#include <hip/hip_runtime.h>
#include <math.h>
#include <float.h>

#define NB    65536
#define DIN   1408
#define PDIM  256
#define KCB   64
#define TAU   3e-4f   // bf16x3 GEMM dist error ~3e-5 -> 7x margin; fp64 refine covers flags

// ---------------- workspace layout ----------------
// [0]       int    cnt (ambiguous-row counter; zeroed via memsetAsync)
// [64]      int    cand[NB]
// [262208]  int    list[NB]
// [524352]  double partials[NB/64]      (1024 * 8 B)
// [1048832] float  g[NB*PDIM]
#define OFF_CNT   0
#define OFF_CAND  64
#define OFF_LIST  262208
#define OFF_PART  524352
#define OFF_G     1048832

typedef short bf16x8 __attribute__((ext_vector_type(8)));
typedef float f32x4  __attribute__((ext_vector_type(4)));

static __device__ __forceinline__ float wave_sum(float v) {
#pragma unroll
  for (int m = 32; m; m >>= 1) v += __shfl_xor(v, m, 64);
  return v;
}

// split fp32 -> bf16 hi (truncation; exact residual) ; lo = x - hi
static __device__ __forceinline__ ushort4 split_hi(float4 v, float4& lo) {
  unsigned int ux = __float_as_uint(v.x), uy = __float_as_uint(v.y),
               uz = __float_as_uint(v.z), uw = __float_as_uint(v.w);
  lo.x = v.x - __uint_as_float(ux & 0xffff0000u);
  lo.y = v.y - __uint_as_float(uy & 0xffff0000u);
  lo.z = v.z - __uint_as_float(uz & 0xffff0000u);
  lo.w = v.w - __uint_as_float(uw & 0xffff0000u);
  return make_ushort4((unsigned short)(ux >> 16), (unsigned short)(uy >> 16),
                      (unsigned short)(uz >> 16), (unsigned short)(uw >> 16));
}
static __device__ __forceinline__ ushort4 rne4(float4 v) {
  return make_ushort4((unsigned short)((__float_as_uint(v.x) + 0x8000u) >> 16),
                      (unsigned short)((__float_as_uint(v.y) + 0x8000u) >> 16),
                      (unsigned short)((__float_as_uint(v.z) + 0x8000u) >> 16),
                      (unsigned short)((__float_as_uint(v.w) + 0x8000u) >> 16));
}

// K2: g = (A @ W) * inv_row_norm via bf16x3 MFMA split GEMM. (unchanged)
#define ROWS 40
__global__ __launch_bounds__(512, 2) void k2_gemm(const float* __restrict__ A,
                                                  const float* __restrict__ W,
                                                  float* __restrict__ g) {
  __shared__ unsigned short As_hi[128][ROWS], As_lo[128][ROWS];
  __shared__ unsigned short Ws_hi[PDIM][ROWS], Ws_lo[PDIM][ROWS];
  __shared__ float rn[128];
  const int t = threadIdx.x;
  const int lane = t & 63;
  const int wm = (t >> 6) >> 2, wn = (t >> 6) & 3;
  const int row0 = blockIdx.x * 128;
  const int ar = t >> 2, ak = (t & 3) << 3;
  const int wcol = t >> 1, wkg = (t & 1) << 4;
  const float* Ap = A + (size_t)(row0 + ar) * DIN + ak;
  const float* Wp = W + (size_t)wkg * PDIM + wcol;

  const f32x4 zero = {0.f, 0.f, 0.f, 0.f};
  f32x4 acc[4][4];
#pragma unroll
  for (int i = 0; i < 4; ++i)
#pragma unroll
    for (int j = 0; j < 4; ++j) acc[i][j] = zero;

  float4 a0 = *(const float4*)(Ap);
  float4 a1 = *(const float4*)(Ap + 4);
  float wv[16];
#pragma unroll
  for (int i = 0; i < 16; ++i) wv[i] = Wp[(size_t)i * PDIM];

  float ss = 0.f;
  for (int k0 = 0; k0 < DIN; k0 += 32) {
    ss += a0.x * a0.x + a0.y * a0.y + a0.z * a0.z + a0.w * a0.w
        + a1.x * a1.x + a1.y * a1.y + a1.z * a1.z + a1.w * a1.w;
    {
      float4 lo;
      ushort4 h = split_hi(a0, lo);
      *(ushort4*)&As_hi[ar][ak] = h;
      *(ushort4*)&As_lo[ar][ak] = rne4(lo);
      h = split_hi(a1, lo);
      *(ushort4*)&As_hi[ar][ak + 4] = h;
      *(ushort4*)&As_lo[ar][ak + 4] = rne4(lo);
#pragma unroll
      for (int q = 0; q < 4; ++q) {
        float4 wva = make_float4(wv[4 * q], wv[4 * q + 1], wv[4 * q + 2], wv[4 * q + 3]);
        float4 wlo;
        ushort4 wh = split_hi(wva, wlo);
        *(ushort4*)&Ws_hi[wcol][wkg + 4 * q] = wh;
        *(ushort4*)&Ws_lo[wcol][wkg + 4 * q] = rne4(wlo);
      }
    }
    __syncthreads();
    const int kn = (k0 + 32 < DIN) ? k0 + 32 : 0;
    float4 na0 = *(const float4*)(Ap + kn);
    float4 na1 = *(const float4*)(Ap + kn + 4);
    float nwv[16];
#pragma unroll
    for (int i = 0; i < 16; ++i) nwv[i] = Wp[(size_t)(kn + i) * PDIM];

    {
      const int fr = lane & 15, fq = (lane >> 4) << 3;
      bf16x8 ah[4], al[4], bh[4], bl[4];
#pragma unroll
      for (int mf = 0; mf < 4; ++mf) {
        const int r = (wm << 6) + (mf << 4) + fr;
        ah[mf] = *(const bf16x8*)&As_hi[r][fq];
        al[mf] = *(const bf16x8*)&As_lo[r][fq];
      }
#pragma unroll
      for (int nf = 0; nf < 4; ++nf) {
        const int n = (wn << 6) + (nf << 4) + fr;
        bh[nf] = *(const bf16x8*)&Ws_hi[n][fq];
        bl[nf] = *(const bf16x8*)&Ws_lo[n][fq];
      }
#pragma unroll
      for (int mf = 0; mf < 4; ++mf)
#pragma unroll
        for (int nf = 0; nf < 4; ++nf) {
          acc[mf][nf] = __builtin_amdgcn_mfma_f32_16x16x32_bf16(ah[mf], bh[nf], acc[mf][nf], 0, 0, 0);
          acc[mf][nf] = __builtin_amdgcn_mfma_f32_16x16x32_bf16(al[mf], bh[nf], acc[mf][nf], 0, 0, 0);
          acc[mf][nf] = __builtin_amdgcn_mfma_f32_16x16x32_bf16(ah[mf], bl[nf], acc[mf][nf], 0, 0, 0);
        }
    }
    __syncthreads();
    a0 = na0; a1 = na1;
#pragma unroll
    for (int i = 0; i < 16; ++i) wv[i] = nwv[i];
  }

  ss += __shfl_xor(ss, 1, 64);
  ss += __shfl_xor(ss, 2, 64);
  if ((t & 3) == 0) rn[ar] = ss;
  __syncthreads();
  if (t < 128) rn[t] = 1.0f / fmaxf(sqrtf(rn[t]), 1e-12f);
  __syncthreads();

  const int er = lane & 15, eq = (lane >> 4) << 2;
#pragma unroll
  for (int mf = 0; mf < 4; ++mf) {
#pragma unroll
    for (int nf = 0; nf < 4; ++nf) {
#pragma unroll
      for (int r = 0; r < 4; ++r) {
        const int row = (wm << 6) + (mf << 4) + eq + r;
        const int col = (wn << 6) + (nf << 4) + er;
        g[(size_t)(row0 + row) * PDIM + col] = acc[mf][nf][r] * rn[row];
      }
    }
  }
}

// K3: 256 threads / 4 waves per block, 64 rows per block.
// Codebook staged in LDS once per block; distance phase is a register-blocked
// 4x4 (k x row) tile per thread: 8 ds_read_b128 feed 64 v_fma per chunk.
#define RB 64
#define CPAD 260   // 65-float4 pitch: row step of 16 rows -> distinct banks
__global__ __launch_bounds__(256, 1) void k3_epilogue(const float* __restrict__ g,
                                                      const float* __restrict__ bvec,
                                                      const float* __restrict__ gamma,
                                                      const float* __restrict__ beta,
                                                      const float* __restrict__ C,
                                                      float* __restrict__ out,
                                                      int* __restrict__ cand,
                                                      int* __restrict__ list,
                                                      int* __restrict__ cnt,
                                                      double* __restrict__ partials) {
  __shared__ float Cs[KCB][CPAD];
  __shared__ float zsh[RB][CPAD];
  __shared__ float ccs[KCB];
  __shared__ float zzs[RB];
  __shared__ float lb[RB];
  __shared__ int idxsh[RB];
  const int t = threadIdx.x;
  const int lane = t & 63, w = t >> 6;
  const int row0 = blockIdx.x * RB;

  // ---- stage codebook (64 KB) into LDS ----
  float4 creg[16];
#pragma unroll
  for (int i = 0; i < 16; ++i)
    creg[i] = *(const float4*)(C + (size_t)((t + (i << 8)) << 2));
#pragma unroll
  for (int i = 0; i < 16; ++i) {
    const int idx = t + (i << 8);
    *(float4*)&Cs[idx >> 6][(idx & 63) << 2] = creg[i];
  }
  __syncthreads();

  // ---- per-code ||c||^2 (one-time) ----
  {
    const int kr = t >> 2, q = t & 3;
    float s = 0.f;
#pragma unroll
    for (int c = 0; c < 16; ++c) {
      float4 v = *(const float4*)&Cs[kr][(q << 6) + (c << 2)];
      s += v.x * v.x + v.y * v.y + v.z * v.z + v.w * v.w;
    }
    s += __shfl_xor(s, 1, 64);
    s += __shfl_xor(s, 2, 64);
    if (q == 0) ccs[kr] = s;
  }

  // ---- phase 1: LN + l2norm for this wave's 16 rows -> zsh ----
  float4 bv = *(const float4*)(bvec + (lane << 2));
  float4 gm = *(const float4*)(gamma + (lane << 2));
  float4 bt = *(const float4*)(beta + (lane << 2));
  float4 gvv[16];
#pragma unroll
  for (int rr = 0; rr < 16; ++rr)
    gvv[rr] = *(const float4*)(g + (size_t)(row0 + (w << 4) + rr) * PDIM + (lane << 2));
#pragma unroll
  for (int rr = 0; rr < 16; ++rr) {
    const int r = (w << 4) + rr;
    float h0 = gvv[rr].x + bv.x, h1 = gvv[rr].y + bv.y;
    float h2 = gvv[rr].z + bv.z, h3 = gvv[rr].w + bv.w;
    float mu = wave_sum(h0 + h1 + h2 + h3) * (1.0f / 256.0f);
    float d0 = h0 - mu, d1 = h1 - mu, d2 = h2 - mu, d3 = h3 - mu;
    float var = wave_sum(d0 * d0 + d1 * d1 + d2 * d2 + d3 * d3) * (1.0f / 256.0f);
    float invs = 1.0f / sqrtf(var + 1e-5f);
    float zp0 = d0 * invs * gm.x + bt.x, zp1 = d1 * invs * gm.y + bt.y;
    float zp2 = d2 * invs * gm.z + bt.z, zp3 = d3 * invs * gm.w + bt.w;
    float nz = wave_sum(zp0 * zp0 + zp1 * zp1 + zp2 * zp2 + zp3 * zp3);
    float zn = 1.0f / fmaxf(sqrtf(nz), 1e-12f);
    float z0 = zp0 * zn, z1 = zp1 * zn, z2 = zp2 * zn, z3 = zp3 * zn;
    float zz = wave_sum(z0 * z0 + z1 * z1 + z2 * z2 + z3 * z3);
    float4 zf = {z0, z1, z2, z3};
    *(float4*)&zsh[r][lane << 2] = zf;
    if (lane == 0) zzs[r] = zz;
  }
  __syncthreads();

  // ---- phase 2: 4x4 (k x row) dot tile per thread over 64 float4 chunks ----
  const int kg = t & 15, rg = t >> 4;
  float p[4][4];   // [ki][ri]
#pragma unroll
  for (int i = 0; i < 4; ++i)
#pragma unroll
    for (int j = 0; j < 4; ++j) p[i][j] = 0.f;

#pragma unroll 2
  for (int c4 = 0; c4 < 64; ++c4) {
    const int co = c4 << 2;
    float4 cv[4], zv[4];
#pragma unroll
    for (int ki = 0; ki < 4; ++ki) cv[ki] = *(const float4*)&Cs[kg + (ki << 4)][co];
#pragma unroll
    for (int ri = 0; ri < 4; ++ri) zv[ri] = *(const float4*)&zsh[rg + (ri << 4)][co];
#pragma unroll
    for (int ki = 0; ki < 4; ++ki)
#pragma unroll
      for (int ri = 0; ri < 4; ++ri) {
        p[ki][ri] = fmaf(cv[ki].x, zv[ri].x, p[ki][ri]);
        p[ki][ri] = fmaf(cv[ki].y, zv[ri].y, p[ki][ri]);
        p[ki][ri] = fmaf(cv[ki].z, zv[ri].z, p[ki][ri]);
        p[ki][ri] = fmaf(cv[ki].w, zv[ri].w, p[ki][ri]);
      }
  }

  // ---- top-2 argmin per row: local scan over ki, butterfly over 16 kg lanes ----
  float ccl[4];
#pragma unroll
  for (int ki = 0; ki < 4; ++ki) ccl[ki] = ccs[kg + (ki << 4)];

  float b1[4], b2[4];
  int i1[4];
#pragma unroll
  for (int ri = 0; ri < 4; ++ri) {
    const float zz = zzs[rg + (ri << 4)];
    b1[ri] = zz - 2.0f * p[0][ri] + ccl[0];
    i1[ri] = kg;
    b2[ri] = FLT_MAX;
#pragma unroll
    for (int ki = 1; ki < 4; ++ki) {
      const float d = zz - 2.0f * p[ki][ri] + ccl[ki];
      if (d < b1[ri]) { b2[ri] = b1[ri]; b1[ri] = d; i1[ri] = kg + (ki << 4); }
      else b2[ri] = fminf(b2[ri], d);
    }
  }
#pragma unroll
  for (int m = 1; m < 16; m <<= 1) {
#pragma unroll
    for (int ri = 0; ri < 4; ++ri) {
      float ob1 = __shfl_xor(b1[ri], m, 64);
      int oi1 = __shfl_xor(i1[ri], m, 64);
      float ob2 = __shfl_xor(b2[ri], m, 64);
      if (ob1 < b1[ri] || (ob1 == b1[ri] && oi1 < i1[ri])) {
        b2[ri] = fminf(b1[ri], ob2);
        b1[ri] = ob1; i1[ri] = oi1;
      } else {
        b2[ri] = fminf(b2[ri], ob1);
      }
    }
  }
  if (kg == 0) {
#pragma unroll
    for (int ri = 0; ri < 4; ++ri) {
      const int r = rg + (ri << 4);
      const int grow = row0 + r;
      cand[grow] = i1[ri];
      out[(size_t)NB * PDIM + grow] = (float)i1[ri];
      idxsh[r] = i1[ri];
      lb[r] = b1[ri];
      if (b2[ri] - b1[ri] < TAU) {
        int wpos = atomicAdd(cnt, 1);
        list[wpos] = grow;
      }
    }
  }
  __syncthreads();

  // ---- out rows = codebook[i1] (served from LDS), loss partial ----
#pragma unroll 4
  for (int rr = 0; rr < 16; ++rr) {
    const int r = (w << 4) + rr;
    const int ii = idxsh[r];
    float4 cv = *(const float4*)&Cs[ii][lane << 2];
    *(float4*)(out + (size_t)(row0 + r) * PDIM + (lane << 2)) = cv;
  }
  if (t == 0) {
    double s = 0.0;
    for (int r = 0; r < RB; ++r) s += (double)lb[r];
    partials[blockIdx.x] = s;
  }
}

// K4: fp64 recompute of flagged rows; fix index, output row, loss partial.
__global__ __launch_bounds__(256) void k4_refine(const float* __restrict__ A,
                                                 const float* __restrict__ W,
                                                 const float* __restrict__ bvec,
                                                 const float* __restrict__ gamma,
                                                 const float* __restrict__ beta,
                                                 const float* __restrict__ C,
                                                 const int* __restrict__ list,
                                                 const int* __restrict__ cnt,
                                                 int* __restrict__ cand,
                                                 float* __restrict__ out,
                                                 double* __restrict__ partials) {
  __shared__ double xs[DIN];
  __shared__ double red[256];
  __shared__ double zd[PDIM];
  __shared__ int idx2[2];
  const int t = threadIdx.x;
  const int n = *cnt;
  for (int it = blockIdx.x; it < n; it += gridDim.x) {
    const int row = list[it];
    __syncthreads();
    for (int i = t; i < DIN; i += 256) xs[i] = (double)A[(size_t)row * DIN + i];
    __syncthreads();
    double s = 0.0;
    for (int i = t; i < DIN; i += 256) s += xs[i] * xs[i];
    red[t] = s; __syncthreads();
    for (int m = 128; m; m >>= 1) { if (t < m) red[t] += red[t + m]; __syncthreads(); }
    const double inv = 1.0 / fmax(sqrt(red[0]), 1e-12);

    double gj = 0.0;
#pragma unroll 8
    for (int k = 0; k < DIN; ++k) gj += xs[k] * (double)W[(size_t)k * PDIM + t];
    const double h = gj * inv + (double)bvec[t];

    __syncthreads(); red[t] = h; __syncthreads();
    for (int m = 128; m; m >>= 1) { if (t < m) red[t] += red[t + m]; __syncthreads(); }
    const double mu = red[0] * (1.0 / 256.0);
    const double d = h - mu;
    __syncthreads(); red[t] = d * d; __syncthreads();
    for (int m = 128; m; m >>= 1) { if (t < m) red[t] += red[t + m]; __syncthreads(); }
    const double invs = 1.0 / sqrt(red[0] * (1.0 / 256.0) + 1e-5);
    const double zp = d * invs * (double)gamma[t] + (double)beta[t];
    __syncthreads(); red[t] = zp * zp; __syncthreads();
    for (int m = 128; m; m >>= 1) { if (t < m) red[t] += red[t + m]; __syncthreads(); }
    const double zn = 1.0 / fmax(sqrt(red[0]), 1e-12);
    const double z = zp * zn;
    zd[t] = z;
    __syncthreads(); red[t] = z * z; __syncthreads();
    for (int m = 128; m; m >>= 1) { if (t < m) red[t] += red[t + m]; __syncthreads(); }
    const double zz = red[0];
    __syncthreads();
    if (t < KCB) {
      double p = 0.0, cc = 0.0;
      for (int c = 0; c < PDIM; ++c) {
        double cv = (double)C[(size_t)t * PDIM + c];
        p += zd[c] * cv; cc += cv * cv;
      }
      red[t] = zz - 2.0 * p + cc;
    }
    __syncthreads();
    if (t == 0) {
      double best = red[0]; int bi = 0;
      for (int k = 1; k < KCB; ++k) if (red[k] < best) { best = red[k]; bi = k; }
      const int old = cand[row];
      idx2[0] = bi; idx2[1] = old;
      if (bi != old) {
        cand[row] = bi;
        out[(size_t)NB * PDIM + row] = (float)bi;
        atomicAdd(&partials[row >> 6], red[bi] - red[old]);
      }
    }
    __syncthreads();
    if (idx2[0] != idx2[1])
      out[(size_t)row * PDIM + t] = C[(size_t)idx2[0] * PDIM + t];
    __syncthreads();
  }
}

// K6: reduce loss partials, write scalar.
__global__ __launch_bounds__(256) void k6_finalize(const double* __restrict__ partials,
                                                   float* __restrict__ out) {
  __shared__ double red[256];
  const int t = threadIdx.x;
  double s = 0.0;
  for (int i = t; i < NB / RB; i += 256) s += partials[i];
  red[t] = s; __syncthreads();
  for (int m = 128; m; m >>= 1) { if (t < m) red[t] += red[t + m]; __syncthreads(); }
  if (t == 0)
    out[(size_t)NB * PDIM + NB] = (float)(0.25 * red[0] / ((double)NB * (double)PDIM));
}

extern "C" void kernel_launch(void* const* d_in, const int* in_sizes, int n_in,
                              void* d_out, int out_size, void* d_ws, size_t ws_size,
                              hipStream_t stream) {
  const float* z_frame  = (const float*)d_in[0];
  const float* W        = (const float*)d_in[1];
  const float* bvec     = (const float*)d_in[2];
  const float* gamma    = (const float*)d_in[3];
  const float* beta     = (const float*)d_in[4];
  const float* codebook = (const float*)d_in[5];
  float* out = (float*)d_out;

  char* ws = (char*)d_ws;
  int*    cnt      = (int*)(ws + OFF_CNT);
  int*    cand     = (int*)(ws + OFF_CAND);
  int*    list     = (int*)(ws + OFF_LIST);
  double* partials = (double*)(ws + OFF_PART);
  float*  g        = (float*)(ws + OFF_G);

  hipMemsetAsync(ws + OFF_CNT, 0, 64, stream);

  k2_gemm<<<NB / 128, 512, 0, stream>>>(z_frame, W, g);
  k3_epilogue<<<NB / RB, 256, 0, stream>>>(g, bvec, gamma, beta, codebook,
                                           out, cand, list, cnt, partials);
  k4_refine<<<256, 256, 0, stream>>>(z_frame, W, bvec, gamma, beta, codebook,
                                     list, cnt, cand, out, partials);
  k6_finalize<<<1, 256, 0, stream>>>(partials, out);
}